// Round 4
// baseline (238.623 us; speedup 1.0000x reference)
//
#include <hip/hip_runtime.h>

typedef _Float16 f16x8 __attribute__((ext_vector_type(8)));
typedef float f32x4 __attribute__((ext_vector_type(4)));
typedef unsigned short u16;
typedef u16 u16x8 __attribute__((ext_vector_type(8)));
typedef u16 u16x4 __attribute__((ext_vector_type(4)));

// ---------- fp16 <-> fp32 helpers ----------
__device__ __forceinline__ u16 f2h_bits(float f) {
    _Float16 h = (_Float16)f;           // RNE
    return __builtin_bit_cast(u16, h);
}
__device__ __forceinline__ float h2f(u16 b) {
    return (float)__builtin_bit_cast(_Float16, b);
}

// async global->LDS, 16B per lane. LDS dest must be wave-uniform base +
// lane*16; per-thread t*16 satisfies that.
typedef __attribute__((address_space(1))) unsigned int gu32_as1;
typedef __attribute__((address_space(3))) unsigned int lu32_as3;
__device__ __forceinline__ void gload16(const u16* g, u16* l) {
    __builtin_amdgcn_global_load_lds((gu32_as1*)g, (lu32_as3*)l, 16, 0, 0);
}

// =====================================================================
// GEMM: C[M,N] = alpha * A[M,K] * Bt[N,K]^T  (fp16 bits, row-major
// k-contiguous). BM=BN=128, BK=32, 256 threads (4 waves, 2x2 grid, each
// wave 64x64 via 4x4 mfma_f32_16x16x32_f16 -> 16 MFMA per k-step).
//
// ROUND-4 STRUCTURE: counted-vmcnt pipeline at multi-block occupancy.
// Rounds 0-3 post-mortem: every prior variant drained ALL outstanding
// vmem at each K-step boundary (__syncthreads' implicit vmcnt(0), or a
// too-short stage->drain window) -> latency-bound at ~24% MfmaUtil
// regardless of schedule. This version keeps loads in flight ACROSS the
// barrier (AITER/T4 pattern: vmcnt never 0 in steady state):
//
//   3-deep LDS buffers (48 KB total, 3 blocks/CU).
//   iter k: ds_read buf[k%3] (staged at k-2, landed since k-1)
//           STAGE tile k+2 -> buf[(k+2)%3]
//           16x MFMA (compiler inserts counted lgkmcnt)
//           s_waitcnt vmcnt(4)   <- previous stage landed; newest 4 in flight
//           s_barrier (raw: no implicit drain) + sched_barrier(0) fence
//
// Hazards: reads@k drained before barrier@k (MFMA reg-interlock, program
// order); stage@k+1 overwrites buf[k%3] only after barrier@k. Reads@k
// see buf contents published by vmcnt(4)@k-1 + barrier@k-1. Tail: at
// k==NT-2 no new stage -> vmcnt(0) so tile NT-1 is guaranteed landed.
//
// LDS per matrix: [buf:3][row:128][slot:4][8] u16 (8 KB per buf).
// Swizzle (proven 0-conflict): slot s' at row r holds global seg
// s'^((r>>1)&3). global_load_lds writes linearly at t*8 u16; per-lane
// GLOBAL seg is pre-swizzled: (t&3)^((t>>3)&3). Fragment reads use slot
// quad^((l16>>1)&3).
//
// MODE: 0 = plain u16 store; 1 = EXPSUM (store exp(alpha*s), atomicAdd
// row sums); 2 = QKV (bn<16 -> QK store ldc=2048; bn>=16 -> write V
// TRANSPOSED into vt[1024][4096]).
// Requires Ksplit % 32 == 0, Ksplit/32 >= 4. gridDim.z = split-K.
// =====================================================================
template <int MODE>
__global__ __launch_bounds__(256, 3) void gemm_bt(
    const u16* __restrict__ A, int lda,
    const u16* __restrict__ B, int ldb,
    u16* __restrict__ C, int ldc,
    int Ksplit, float alpha, size_t c_z_stride,
    int bnW, int bmW, int numPanelX,
    float* __restrict__ rowsum, u16* __restrict__ vt)
{
    __shared__ __attribute__((aligned(16))) u16 As[12288];  // 3 x 8 KB
    __shared__ __attribute__((aligned(16))) u16 Bs[12288];  // 3 x 8 KB

    const int t    = threadIdx.x;
    const int lane = t & 63;
    const int wave = t >> 6;
    const int wm   = wave & 1;
    const int wn   = wave >> 1;
    const int l16  = lane & 15;
    const int quad = lane >> 4;

    // 2D-panel XCD mapping (grid x*y divisible by 8)
    const int lin = blockIdx.y * gridDim.x + blockIdx.x;
    const int xcd = lin & 7;
    const int idx = lin >> 3;
    const int px  = xcd % numPanelX;
    const int py  = xcd / numPanelX;
    const int bn  = px * bnW + idx % bnW;
    const int bm  = py * bmW + idx / bnW;

    const int kz = blockIdx.z;
    A += (size_t)kz * Ksplit;
    B += (size_t)kz * Ksplit;
    C += (size_t)kz * c_z_stride;

    // staging: thread t owns LDS rows (t>>2) and (t>>2)+64, slot t&3;
    // fetches pre-swizzled global segment (t&3)^((t>>3)&3)  [0 conflicts]
    const int srow = t >> 2;
    const int scol = ((t & 3) ^ ((t >> 3) & 3)) * 8;

    const u16* Ag = A + (size_t)(bm * 128 + srow) * lda + scol;
    const u16* Bg = B + (size_t)(bn * 128 + srow) * ldb + scol;
    const size_t a64 = (size_t)64 * lda;   // row+64: same swizzle term
    const size_t b64 = (size_t)64 * ldb;

    u16* AsD = &As[t * 8];
    u16* BsD = &Bs[t * 8];

#define STAGE(bufv, k0) do {                                     \
        gload16(Ag + (k0),       AsD + (bufv) * 4096);           \
        gload16(Ag + (k0) + a64, AsD + (bufv) * 4096 + 2048);    \
        gload16(Bg + (k0),       BsD + (bufv) * 4096);           \
        gload16(Bg + (k0) + b64, BsD + (bufv) * 4096 + 2048);    \
    } while (0)

    // fragment base pointers (row-major [128][32], swizzled slots)
    const int fseg = (quad ^ ((l16 >> 1) & 3)) * 8;
    const u16* Afr = &As[(wm * 64 + l16) * 32 + fseg];
    const u16* Bfr = &Bs[(wn * 64 + l16) * 32 + fseg];

    f32x4 acc[4][4] = {};

    const int NT = Ksplit >> 5;

    // prologue: stage tiles 0,1 into bufs 0,1; wait tile 0 only
    STAGE(0, 0);
    STAGE(1, 32);
    asm volatile("s_waitcnt vmcnt(4)" ::: "memory");
    __builtin_amdgcn_s_barrier();
    __builtin_amdgcn_sched_barrier(0);

    int cur = 0;
    for (int k = 0; k < NT; ++k) {
        // ---- fragment reads from buf[cur] ----
        f16x8 af[4], bfv[4];
#pragma unroll
        for (int i = 0; i < 4; i++)
            af[i]  = *(const f16x8*)(Afr + cur * 4096 + i * 512);
#pragma unroll
        for (int i = 0; i < 4; i++)
            bfv[i] = *(const f16x8*)(Bfr + cur * 4096 + i * 512);

        // ---- stage tile k+2 into buf[(cur+2)%3] ----
        if (k + 2 < NT) {
            const int nxt = (cur == 0) ? 2 : cur - 1;   // cur+2 mod 3
            STAGE(nxt, (k + 2) * 32);
        }

        // ---- 16 MFMA (counted lgkmcnt inserted by compiler) ----
#pragma unroll
        for (int mi = 0; mi < 4; mi++)
#pragma unroll
            for (int ni = 0; ni < 4; ni++)
                acc[mi][ni] = __builtin_amdgcn_mfma_f32_16x16x32_f16(
                    af[mi], bfv[ni], acc[mi][ni], 0, 0, 0);

        // ---- counted wait: tile k+1's stage landed; k+2's in flight ----
        if (k + 2 < NT)       asm volatile("s_waitcnt vmcnt(4)" ::: "memory");
        else if (k == NT - 2) asm volatile("s_waitcnt vmcnt(0)" ::: "memory");
        __builtin_amdgcn_s_barrier();
        __builtin_amdgcn_sched_barrier(0);

        cur = (cur == 2) ? 0 : cur + 1;
    }
#undef STAGE

    // epilogue: C/D layout col = lane&15, row = quad*4 + reg
    const int crow = bm * 128 + wm * 64 + quad * 4;
    const int ccol = bn * 128 + wn * 64 + l16;

    if (MODE == 1) {
        float rs[4][4];
#pragma unroll
        for (int mi = 0; mi < 4; mi++)
#pragma unroll
            for (int r = 0; r < 4; r++) rs[mi][r] = 0.f;
#pragma unroll
        for (int mi = 0; mi < 4; mi++) {
#pragma unroll
            for (int ni = 0; ni < 4; ni++) {
#pragma unroll
                for (int r = 0; r < 4; r++) {
                    float e = __expf(acc[mi][ni][r] * alpha);
                    rs[mi][r] += e;
                    C[(size_t)(crow + mi * 16 + r) * ldc + (ccol + ni * 16)] = f2h_bits(e);
                }
            }
        }
#pragma unroll
        for (int mi = 0; mi < 4; mi++) {
#pragma unroll
            for (int r = 0; r < 4; r++) {
                float s = rs[mi][r];
#pragma unroll
                for (int o = 1; o < 16; o <<= 1) s += __shfl_xor(s, o);
                if (l16 == 0)
                    atomicAdd(&rowsum[crow + mi * 16 + r], s);
            }
        }
    } else if (MODE == 2 && bn >= 16) {
        // V tile -> write transposed into vt[1024][4096]
#pragma unroll
        for (int ni = 0; ni < 4; ni++) {
            const int cV = (bn - 16) * 128 + wn * 64 + ni * 16 + l16;
#pragma unroll
            for (int mi = 0; mi < 4; mi++) {
                u16x4 o;
#pragma unroll
                for (int r = 0; r < 4; r++) o[r] = f2h_bits(acc[mi][ni][r]);
                *(u16x4*)(vt + (size_t)cV * 4096 + crow + mi * 16) = o;
            }
        }
    } else {
#pragma unroll
        for (int mi = 0; mi < 4; mi++)
#pragma unroll
            for (int ni = 0; ni < 4; ni++)
#pragma unroll
                for (int r = 0; r < 4; r++)
                    C[(size_t)(crow + mi * 16 + r) * ldc + (ccol + ni * 16)] =
                        f2h_bits(acc[mi][ni][r] * alpha);
    }
}

// =====================================================================
// cast fp32 -> fp16 bits, 4 elems/thread
// =====================================================================
__global__ __launch_bounds__(256) void cast_to_f16(
    const float* __restrict__ in, u16* __restrict__ out, int n)
{
    int i = (blockIdx.x * 256 + threadIdx.x) * 4;
    if (i + 3 < n) {
        float4 v = *(const float4*)(in + i);
        ushort4 o;
        o.x = f2h_bits(v.x);
        o.y = f2h_bits(v.y);
        o.z = f2h_bits(v.z);
        o.w = f2h_bits(v.w);
        *(ushort4*)(out + i) = o;
    }
}

// =====================================================================
// transpose the 3 weight matrices [1024][1024] fp32 -> packed fp16
// Wt[3072][1024]; z selects the matrix. 32x32 LDS tile, block (32,8).
// =====================================================================
__global__ __launch_bounds__(256) void transpose_w3(
    const float* __restrict__ W0, const float* __restrict__ W1,
    const float* __restrict__ W2, u16* __restrict__ out)
{
    const float* in = (blockIdx.z == 0) ? W0 : (blockIdx.z == 1) ? W1 : W2;
    u16* o = out + (size_t)blockIdx.z * 1024 * 1024;
    __shared__ float tile[32][33];
    const int bx = blockIdx.x * 32;
    const int by = blockIdx.y * 32;
    const int tx = threadIdx.x, ty = threadIdx.y;
#pragma unroll
    for (int j = 0; j < 4; j++)
        tile[ty + j * 8][tx] = in[(size_t)(by + ty + j * 8) * 1024 + bx + tx];
    __syncthreads();
#pragma unroll
    for (int j = 0; j < 4; j++)
        o[(size_t)(bx + ty + j * 8) * 1024 + by + tx] = f2h_bits(tile[tx][ty + j * 8]);
}

// =====================================================================
// zero a float array (n multiple of 1024)
// =====================================================================
__global__ __launch_bounds__(256) void zero_f32(float* __restrict__ p, int n)
{
    int i = (blockIdx.x * 256 + threadIdx.x) * 4;
    if (i + 3 < n) *(float4*)(p + i) = float4{0.f, 0.f, 0.f, 0.f};
}

// =====================================================================
// out = (P0+P1+P2+P3)/l[row]; partials fp16, 8 elems/thread
// =====================================================================
__global__ __launch_bounds__(256) void add_div4(
    const u16* __restrict__ P, const float* __restrict__ l,
    float* __restrict__ o)
{
    const size_t zs = (size_t)4096 * 1024;
    int i = (blockIdx.x * 256 + threadIdx.x) * 8;
    float inv = 1.0f / l[i >> 10];
    float s[8] = {};
#pragma unroll
    for (int z = 0; z < 4; z++) {
        u16x8 h = *(const u16x8*)(P + z * zs + i);
#pragma unroll
        for (int j = 0; j < 8; j++) s[j] += h2f(h[j]);
    }
    float4 lo{s[0] * inv, s[1] * inv, s[2] * inv, s[3] * inv};
    float4 hi{s[4] * inv, s[5] * inv, s[6] * inv, s[7] * inv};
    *(float4*)(o + i) = lo;
    *(float4*)(o + i + 4) = hi;
}

// =====================================================================
// launch
//
// Workspace liveness (MiB):
//   xb [0,8)    live 1-3          Wt [8,14)  live 2-3
//   QK [14,30)  live 3-5          Vt [64,72) live 3-6
//   Sb [32,64)  live 5-6          lr [72,+16K) zero 4, atomics 5, read 7
//   P  [0,32)   written 6 (xb/Wt/QK dead), read 7
// =====================================================================
extern "C" void kernel_launch(void* const* d_in, const int* in_sizes, int n_in,
                              void* d_out, int out_size, void* d_ws, size_t ws_size,
                              hipStream_t stream)
{
    (void)in_sizes; (void)n_in; (void)out_size; (void)ws_size;
    const float* x  = (const float*)d_in[0];
    const float* Wq = (const float*)d_in[1];
    const float* Wk = (const float*)d_in[2];
    const float* Wv = (const float*)d_in[3];
    float* out = (float*)d_out;
    char* ws = (char*)d_ws;

    u16* xb  = (u16*)(ws);                              //  8 MiB
    u16* Wt  = (u16*)(ws + ((size_t)8  << 20));         //  6 MiB
    u16* QK  = (u16*)(ws + ((size_t)14 << 20));         // 16 MiB [4096][2048]
    u16* Sb  = (u16*)(ws + ((size_t)32 << 20));         // 32 MiB [4096][4096]
    u16* Vt  = (u16*)(ws + ((size_t)64 << 20));         //  8 MiB [1024][4096]
    float* lr = (float*)(ws + ((size_t)72 << 20));      // 16 KiB row sums
    u16* P   = (u16*)(ws);                              // 32 MiB: 4 x [4096][1024]

    const int S = 4096, D = 1024;
    dim3 tb(32, 8);

    // 1) cast x to fp16
    cast_to_f16<<<(S * D) / (4 * 256), 256, 0, stream>>>(x, xb, S * D);

    // 2) transpose-cast all three W's into packed Wt[3072][1024]
    transpose_w3<<<dim3(32, 32, 3), tb, 0, stream>>>(Wq, Wk, Wv, Wt);

    // 3) [Q|K] = x @ [Wq|Wk], V^T written directly (M=4096, N=3072, K=1024)
    gemm_bt<2><<<dim3(3072 / 128, S / 128, 1), 256, 0, stream>>>(
        xb, D, Wt, D, QK, 2048, D, 1.0f, 0, 6, 16, 4, nullptr, Vt);

    // 4) zero row-sum accumulator
    zero_f32<<<S / (4 * 256), 256, 0, stream>>>(lr, S);

    // 5) Sb = exp((Q @ K^T)/32) + rowsum atomics  (M=N=4096, K=1024)
    gemm_bt<1><<<dim3(S / 128, S / 128, 1), 256, 0, stream>>>(
        QK, 2048, QK + 1024, 2048, Sb, S, D, 0.03125f, 0, 8, 16, 4, lr, nullptr);

    // 6) P[z] = expS @ V, split-K=4 (M=4096, N=1024, Ksplit=1024)
    gemm_bt<0><<<dim3(D / 128, S / 128, 4), 256, 0, stream>>>(
        Sb, S, Vt, S, P, D, 1024, 1.0f, (size_t)S * D, 4, 8, 2, nullptr, nullptr);

    // 7) out = (P0+P1+P2+P3) / l[row]
    add_div4<<<(S * D) / (8 * 256), 256, 0, stream>>>(P, lr, out);
}

// Round 5
// 216.392 us; speedup vs baseline: 1.1027x; 1.1027x over previous
//
#include <hip/hip_runtime.h>

typedef _Float16 f16x8 __attribute__((ext_vector_type(8)));
typedef float f32x4 __attribute__((ext_vector_type(4)));
typedef unsigned short u16;
typedef u16 u16x8 __attribute__((ext_vector_type(8)));
typedef u16 u16x4 __attribute__((ext_vector_type(4)));

// ---------- fp16 <-> fp32 helpers ----------
__device__ __forceinline__ u16 f2h_bits(float f) {
    _Float16 h = (_Float16)f;           // RNE
    return __builtin_bit_cast(u16, h);
}
__device__ __forceinline__ float h2f(u16 b) {
    return (float)__builtin_bit_cast(_Float16, b);
}

// async global->LDS, 16B per lane. LDS dest must be wave-uniform base +
// lane*16; per-thread t*16 satisfies that.
typedef __attribute__((address_space(1))) unsigned int gu32_as1;
typedef __attribute__((address_space(3))) unsigned int lu32_as3;
__device__ __forceinline__ void gload16(const u16* g, u16* l) {
    __builtin_amdgcn_global_load_lds((gu32_as1*)g, (lu32_as3*)l, 16, 0, 0);
}

// =====================================================================
// GEMM: C[M,N] = alpha * A[M,K] * Bt[N,K]^T  (fp16 bits, k-contiguous).
//
// ROUND-5 STRUCTURE: 256x256 tile, BK=32, 512 threads = 8 waves (2M x
// 4N), wave tile 128x64 = acc[8][4] f32x4, 32 MFMA + 12 ds_read_b128
// per wave per K-step (FLOP/LDS-byte 1.33x the 64x64-wave rounds).
//
// DEEP COVER, MINIMAL PINNING (rounds 0-4 post-mortem: all schedules
// with <=1.5 K-steps of load->wait cover plateaued at 20-25% MfmaUtil;
// round-2 proved 1 block/CU is fine; round-4 proved occupancy drops
// hurt; m141 proved sched_barrier pinning hurts):
//   4-deep LDS buffer rotation (4 x 32 KB = 128 KiB). Step k:
//     reads buf[k&3]  (tile k: staged at step k-3, drained at k-1)
//     STAGE tile k+3 -> buf[(k+3)&3]   (never the buffer being read)
//     32 MFMA (compiler inserts counted lgkmcnt)
//     s_waitcnt vmcnt(8)   <- tile k+1 landed; k+2,k+3 stay in flight
//     s_barrier (raw) + empty-asm compiler fence
//   Cover = ~3 K-steps from issue to first wait. vmcnt never 0 until
//   the tail (k==NT-3: 4, k==NT-2: 0). No sched_barrier(0), no setprio,
//   no lgkmcnt asm anywhere: compiler schedules the step body freely.
//
// Hazards: (a) reads@k need tile k landed: my wave's vmcnt@k-1 + other
// waves' published by barrier@k-1 + fence keeps reads below barrier.
// (b) stage@k writes buf[(k+3)&3] = buf[(k-1)&3]: all waves' reads@k-1
// completed before their MFMAs issued (register interlock, compiler
// lgkmcnt), which precede barrier@k-1 arrival -> region dead. (c) reads
// can't hoist above the vmcnt asm ("memory" clobber) or the fence.
//
// LDS per matrix per buf: [row:256][slot:4][8] u16 (16 KB). Swizzle
// (proven 0-conflict): slot s at row r holds global seg s^((r>>1)&3).
// global_load_lds writes linearly at t*8 u16 (t = row*4+slot); per-lane
// GLOBAL seg pre-swizzled: (t&3)^((t>>3)&3). Fragment reads use slot
// quad^((l16>>1)&3).
//
// MODE: 0 plain store; 1 exp(alpha*s)+rowsum atomics; 2 QKV (bn<8 -> QK
// ldc=2048; bn>=8 -> V transposed into vt[1024][4096]).
// Requires Ksplit % 32 == 0, Ksplit/32 >= 3. gridDim.z = split-K.
// =====================================================================
template <int MODE>
__global__ __launch_bounds__(512, 2) void gemm_bt(
    const u16* __restrict__ A, int lda,
    const u16* __restrict__ B, int ldb,
    u16* __restrict__ C, int ldc,
    int Ksplit, float alpha, size_t c_z_stride,
    int bnW, int bmW, int numPanelX,
    float* __restrict__ rowsum, u16* __restrict__ vt)
{
    __shared__ __attribute__((aligned(16))) u16 As[32768];  // 4 x 16 KB
    __shared__ __attribute__((aligned(16))) u16 Bs[32768];  // 4 x 16 KB

    const int t    = threadIdx.x;        // 0..511
    const int lane = t & 63;
    const int wave = t >> 6;             // 0..7
    const int wm   = wave >> 2;          // 0..1  (128-row half)
    const int wn   = wave & 3;           // 0..3  (64-col quarter)
    const int l16  = lane & 15;
    const int quad = lane >> 4;

    // 2D-panel XCD mapping (grid x*y divisible by 8)
    const int lin = blockIdx.y * gridDim.x + blockIdx.x;
    const int xcd = lin & 7;
    const int idx = lin >> 3;
    const int px  = xcd % numPanelX;
    const int py  = xcd / numPanelX;
    const int bn  = px * bnW + idx % bnW;
    const int bm  = py * bmW + idx / bnW;

    const int kz = blockIdx.z;
    A += (size_t)kz * Ksplit;
    B += (size_t)kz * Ksplit;
    C += (size_t)kz * c_z_stride;

    // staging: thread t -> row t>>2 (and +128), slot t&3; global seg
    // pre-swizzled so the linear LDS write lands swizzled. [0 conflicts]
    const int srow = t >> 2;
    const int sseg = ((t & 3) ^ ((t >> 3) & 3)) * 8;

    const u16* Ag = A + (size_t)(bm * 256 + srow) * lda + sseg;
    const u16* Bg = B + (size_t)(bn * 256 + srow) * ldb + sseg;
    const size_t a128 = (size_t)128 * lda;   // row+128: same swizzle term
    const size_t b128 = (size_t)128 * ldb;

    u16* AsD = &As[t * 8];
    u16* BsD = &Bs[t * 8];

    // tile kt (k-range [kt*32, kt*32+32)) -> buf bufv. 4 loads/thread.
#define STAGE(bufv, kt) do {                                       \
        const u16* _ga = Ag + (size_t)(kt) * 32;                   \
        const u16* _gb = Bg + (size_t)(kt) * 32;                   \
        u16* _la = AsD + (bufv) * 8192;                            \
        u16* _lb = BsD + (bufv) * 8192;                            \
        gload16(_ga,        _la);            /* A rows 0-127   */  \
        gload16(_ga + a128, _la + 4096);     /* A rows 128-255 */  \
        gload16(_gb,        _lb);            /* B rows 0-127   */  \
        gload16(_gb + b128, _lb + 4096);     /* B rows 128-255 */  \
    } while (0)

    // fragment base pointers ([row:256][slot:4][8], swizzled slots)
    const int fslot = (quad ^ ((l16 >> 1) & 3)) * 8;
    const u16* Afr = &As[wm * 4096 + l16 * 32 + fslot];   // rows wm*128+l16
    const u16* Bfr = &Bs[wn * 2048 + l16 * 32 + fslot];   // rows wn*64+l16

    f32x4 acc[8][4] = {};

    const int NT = Ksplit >> 5;

    // prologue: stage tiles 0,1,2; wait tile 0 only
    STAGE(0, 0);
    STAGE(1, 1);
    STAGE(2, 2);
    asm volatile("s_waitcnt vmcnt(8)" ::: "memory");
    __builtin_amdgcn_s_barrier();
    asm volatile("" ::: "memory");

    for (int k = 0; k < NT; ++k) {
        const int buf = k & 3;

        // ---- 12 fragment reads from buf (consumed by this step's MFMA) ----
        f16x8 af[8], bf[4];
#pragma unroll
        for (int mi = 0; mi < 8; mi++)
            af[mi] = *(const f16x8*)(Afr + buf * 8192 + mi * 512);
#pragma unroll
        for (int nj = 0; nj < 4; nj++)
            bf[nj] = *(const f16x8*)(Bfr + buf * 8192 + nj * 512);

        // ---- stage tile k+3 into buf[(k+3)&3] (not read until k+3) ----
        if (k + 3 < NT) STAGE((k + 3) & 3, k + 3);

        // ---- 32 MFMA; compiler interleaves + inserts counted lgkmcnt ----
#pragma unroll
        for (int mi = 0; mi < 8; mi++)
#pragma unroll
            for (int nj = 0; nj < 4; nj++)
                acc[mi][nj] = __builtin_amdgcn_mfma_f32_16x16x32_f16(
                    af[mi], bf[nj], acc[mi][nj], 0, 0, 0);

        // ---- counted wait: tile k+1 landed; k+2,k+3 stay in flight ----
        if (k < NT - 3)       asm volatile("s_waitcnt vmcnt(8)" ::: "memory");
        else if (k == NT - 3) asm volatile("s_waitcnt vmcnt(4)" ::: "memory");
        else if (k == NT - 2) asm volatile("s_waitcnt vmcnt(0)" ::: "memory");
        __builtin_amdgcn_s_barrier();
        asm volatile("" ::: "memory");   // compiler fence: reads stay below
    }
#undef STAGE

    // epilogue: C/D layout col = lane&15, row = quad*4 + reg
    const int crow = bm * 256 + wm * 128 + quad * 4;
    const int ccol = bn * 256 + wn * 64 + l16;

    if (MODE == 1) {
        float rs[8][4];
#pragma unroll
        for (int mi = 0; mi < 8; mi++)
#pragma unroll
            for (int r = 0; r < 4; r++) rs[mi][r] = 0.f;
#pragma unroll
        for (int mi = 0; mi < 8; mi++) {
#pragma unroll
            for (int ni = 0; ni < 4; ni++) {
#pragma unroll
                for (int r = 0; r < 4; r++) {
                    float e = __expf(acc[mi][ni][r] * alpha);
                    rs[mi][r] += e;
                    C[(size_t)(crow + mi * 16 + r) * ldc + (ccol + ni * 16)] = f2h_bits(e);
                }
            }
        }
#pragma unroll
        for (int mi = 0; mi < 8; mi++) {
#pragma unroll
            for (int r = 0; r < 4; r++) {
                float s = rs[mi][r];
#pragma unroll
                for (int o = 1; o < 16; o <<= 1) s += __shfl_xor(s, o);
                if (l16 == 0)
                    atomicAdd(&rowsum[crow + mi * 16 + r], s);
            }
        }
    } else if (MODE == 2 && bn >= 8) {
        // V tile -> write transposed into vt[1024][4096]
#pragma unroll
        for (int ni = 0; ni < 4; ni++) {
            const int cV = (bn - 8) * 256 + wn * 64 + ni * 16 + l16;
#pragma unroll
            for (int mi = 0; mi < 8; mi++) {
                u16x4 o;
#pragma unroll
                for (int r = 0; r < 4; r++) o[r] = f2h_bits(acc[mi][ni][r]);
                *(u16x4*)(vt + (size_t)cV * 4096 + crow + mi * 16) = o;
            }
        }
    } else {
#pragma unroll
        for (int mi = 0; mi < 8; mi++)
#pragma unroll
            for (int ni = 0; ni < 4; ni++)
#pragma unroll
                for (int r = 0; r < 4; r++)
                    C[(size_t)(crow + mi * 16 + r) * ldc + (ccol + ni * 16)] =
                        f2h_bits(acc[mi][ni][r] * alpha);
    }
}

// =====================================================================
// cast fp32 -> fp16 bits, 4 elems/thread
// =====================================================================
__global__ __launch_bounds__(256) void cast_to_f16(
    const float* __restrict__ in, u16* __restrict__ out, int n)
{
    int i = (blockIdx.x * 256 + threadIdx.x) * 4;
    if (i + 3 < n) {
        float4 v = *(const float4*)(in + i);
        ushort4 o;
        o.x = f2h_bits(v.x);
        o.y = f2h_bits(v.y);
        o.z = f2h_bits(v.z);
        o.w = f2h_bits(v.w);
        *(ushort4*)(out + i) = o;
    }
}

// =====================================================================
// transpose the 3 weight matrices [1024][1024] fp32 -> packed fp16
// Wt[3072][1024]; z selects the matrix. 32x32 LDS tile, block (32,8).
// =====================================================================
__global__ __launch_bounds__(256) void transpose_w3(
    const float* __restrict__ W0, const float* __restrict__ W1,
    const float* __restrict__ W2, u16* __restrict__ out)
{
    const float* in = (blockIdx.z == 0) ? W0 : (blockIdx.z == 1) ? W1 : W2;
    u16* o = out + (size_t)blockIdx.z * 1024 * 1024;
    __shared__ float tile[32][33];
    const int bx = blockIdx.x * 32;
    const int by = blockIdx.y * 32;
    const int tx = threadIdx.x, ty = threadIdx.y;
#pragma unroll
    for (int j = 0; j < 4; j++)
        tile[ty + j * 8][tx] = in[(size_t)(by + ty + j * 8) * 1024 + bx + tx];
    __syncthreads();
#pragma unroll
    for (int j = 0; j < 4; j++)
        o[(size_t)(bx + ty + j * 8) * 1024 + by + tx] = f2h_bits(tile[tx][ty + j * 8]);
}

// =====================================================================
// zero a float array (n multiple of 1024)
// =====================================================================
__global__ __launch_bounds__(256) void zero_f32(float* __restrict__ p, int n)
{
    int i = (blockIdx.x * 256 + threadIdx.x) * 4;
    if (i + 3 < n) *(float4*)(p + i) = float4{0.f, 0.f, 0.f, 0.f};
}

// =====================================================================
// out = (P0+P1+P2+P3)/l[row]; partials fp16, 8 elems/thread
// =====================================================================
__global__ __launch_bounds__(256) void add_div4(
    const u16* __restrict__ P, const float* __restrict__ l,
    float* __restrict__ o)
{
    const size_t zs = (size_t)4096 * 1024;
    int i = (blockIdx.x * 256 + threadIdx.x) * 8;
    float inv = 1.0f / l[i >> 10];
    float s[8] = {};
#pragma unroll
    for (int z = 0; z < 4; z++) {
        u16x8 h = *(const u16x8*)(P + z * zs + i);
#pragma unroll
        for (int j = 0; j < 8; j++) s[j] += h2f(h[j]);
    }
    float4 lo{s[0] * inv, s[1] * inv, s[2] * inv, s[3] * inv};
    float4 hi{s[4] * inv, s[5] * inv, s[6] * inv, s[7] * inv};
    *(float4*)(o + i) = lo;
    *(float4*)(o + i + 4) = hi;
}

// =====================================================================
// launch
//
// Workspace liveness (MiB):
//   xb [0,8)    live 1-3          Wt [8,14)  live 2-3
//   QK [14,30)  live 3-5          Vt [64,72) live 3-6
//   Sb [32,64)  live 5-6          lr [72,+16K) zero 4, atomics 5, read 7
//   P  [0,32)   written 6 (xb/Wt/QK dead), read 7
// =====================================================================
extern "C" void kernel_launch(void* const* d_in, const int* in_sizes, int n_in,
                              void* d_out, int out_size, void* d_ws, size_t ws_size,
                              hipStream_t stream)
{
    (void)in_sizes; (void)n_in; (void)out_size; (void)ws_size;
    const float* x  = (const float*)d_in[0];
    const float* Wq = (const float*)d_in[1];
    const float* Wk = (const float*)d_in[2];
    const float* Wv = (const float*)d_in[3];
    float* out = (float*)d_out;
    char* ws = (char*)d_ws;

    u16* xb  = (u16*)(ws);                              //  8 MiB
    u16* Wt  = (u16*)(ws + ((size_t)8  << 20));         //  6 MiB
    u16* QK  = (u16*)(ws + ((size_t)14 << 20));         // 16 MiB [4096][2048]
    u16* Sb  = (u16*)(ws + ((size_t)32 << 20));         // 32 MiB [4096][4096]
    u16* Vt  = (u16*)(ws + ((size_t)64 << 20));         //  8 MiB [1024][4096]
    float* lr = (float*)(ws + ((size_t)72 << 20));      // 16 KiB row sums
    u16* P   = (u16*)(ws);                              // 32 MiB: 4 x [4096][1024]

    const int S = 4096, D = 1024;
    dim3 tb(32, 8);

    // 1) cast x to fp16
    cast_to_f16<<<(S * D) / (4 * 256), 256, 0, stream>>>(x, xb, S * D);

    // 2) transpose-cast all three W's into packed Wt[3072][1024]
    transpose_w3<<<dim3(32, 32, 3), tb, 0, stream>>>(Wq, Wk, Wv, Wt);

    // 3) [Q|K] = x @ [Wq|Wk], V^T written directly (M=4096, N=3072, K=1024)
    //    grid 12x16=192 blocks; panels: bnW=3, bmW=8, numPanelX=4
    gemm_bt<2><<<dim3(12, 16, 1), 512, 0, stream>>>(
        xb, D, Wt, D, QK, 2048, D, 1.0f, 0, 3, 8, 4, nullptr, Vt);

    // 4) zero row-sum accumulator
    zero_f32<<<S / (4 * 256), 256, 0, stream>>>(lr, S);

    // 5) Sb = exp((Q @ K^T)/32) + rowsum atomics  (M=N=4096, K=1024)
    //    grid 16x16=256 blocks; panels: bnW=4, bmW=8, numPanelX=4
    gemm_bt<1><<<dim3(16, 16, 1), 512, 0, stream>>>(
        QK, 2048, QK + 1024, 2048, Sb, S, D, 0.03125f, 0, 4, 8, 4, lr, nullptr);

    // 6) P[z] = expS @ V, split-K=4 (M=4096, N=1024, Ksplit=1024)
    //    grid 4x16x4; panels per z: bnW=1, bmW=8, numPanelX=4
    gemm_bt<0><<<dim3(4, 16, 4), 512, 0, stream>>>(
        Sb, S, Vt, S, P, D, 1024, 1.0f, (size_t)S * D, 1, 8, 4, nullptr, nullptr);

    // 7) out = (P0+P1+P2+P3) / l[row]
    add_div4<<<(S * D) / (8 * 256), 256, 0, stream>>>(P, lr, out);
}